// Round 5
// baseline (328.852 us; speedup 1.0000x reference)
//
#include <hip/hip_runtime.h>
#include <math.h>

#define NUM_CLASSES 10
#define A_BLOCKS 512
#define B_BLOCKS 1792   // 7 blocks/CU x 256 CUs: LDS 20.7KiB/block caps residency at 7 — 2048 left a 256-block tail

// ws layout (every used word overwritten each call; harness poisons ws with 0xAA):
//   [0)     unsigned pc[A_BLOCKS][NUM_CLASSES]  per-block histograms   (20480 B)
//   [20480) float2   pacc[B_BLOCKS]             per-block partials     (14336 B)
//   [34816) unsigned done                       ticket counter (zeroed by hist_kernel)

__global__ void __launch_bounds__(256) hist_kernel(const int* __restrict__ target,
                                                   unsigned int* __restrict__ pc,
                                                   unsigned int* __restrict__ done, int n) {
    if (blockIdx.x == 0 && threadIdx.x == 0) *done = 0u;  // visible to main via kernel boundary

    unsigned int cnt[NUM_CLASSES];
#pragma unroll
    for (int c = 0; c < NUM_CLASSES; ++c) cnt[c] = 0u;

    const int tid = blockIdx.x * blockDim.x + threadIdx.x;
    const int stride = gridDim.x * blockDim.x;
    const int4* __restrict__ t4 = (const int4*)target;  // harness passes int32 targets
    const int n4 = n >> 2;

    for (int i = tid; i < n4; i += stride) {
        int4 v = t4[i];
#pragma unroll
        for (int c = 0; c < NUM_CLASSES; ++c) {
            cnt[c] += (unsigned int)(v.x == c) + (unsigned int)(v.y == c) +
                      (unsigned int)(v.z == c) + (unsigned int)(v.w == c);
        }
    }

#pragma unroll
    for (int c = 0; c < NUM_CLASSES; ++c) {
        unsigned int v = cnt[c];
        for (int off = 32; off > 0; off >>= 1)
            v += (unsigned int)__shfl_down((int)v, off, 64);
        cnt[c] = v;
    }

    __shared__ unsigned int sh[4][NUM_CLASSES];
    const int wave = threadIdx.x >> 6;
    if ((threadIdx.x & 63) == 0) {
#pragma unroll
        for (int c = 0; c < NUM_CLASSES; ++c) sh[wave][c] = cnt[c];
    }
    __syncthreads();
    if (threadIdx.x < NUM_CLASSES) {
        const int c = threadIdx.x;
        pc[blockIdx.x * NUM_CLASSES + c] = sh[0][c] + sh[1][c] + sh[2][c] + sh[3][c];
    }
}

__global__ void __launch_bounds__(256, 7) main_kernel(const float* __restrict__ outputs,
                                                      const unsigned int* __restrict__ pc,
                                                      float2* __restrict__ pacc,
                                                      unsigned int* __restrict__ done,
                                                      float* __restrict__ out,
                                                      int n, float fn) {
    const int wave = threadIdx.x >> 6;
    const int lane = threadIdx.x & 63;

    // ---- phase 1: reduce per-block histograms -> w[10] (block-local) ----
    unsigned int pw[NUM_CLASSES];
#pragma unroll
    for (int c = 0; c < NUM_CLASSES; ++c) pw[c] = 0u;
#pragma unroll
    for (int r = 0; r < A_BLOCKS / 256; ++r) {
        const unsigned int* row = pc + (threadIdx.x + r * 256) * NUM_CLASSES;
#pragma unroll
        for (int c = 0; c < NUM_CLASSES; ++c) pw[c] += row[c];
    }
#pragma unroll
    for (int c = 0; c < NUM_CLASSES; ++c) {
        unsigned int v = pw[c];
        for (int off = 32; off > 0; off >>= 1)
            v += (unsigned int)__shfl_down((int)v, off, 64);
        pw[c] = v;
    }
    __shared__ unsigned int shw[4][NUM_CLASSES];
    __shared__ float fw[NUM_CLASSES];
    if (lane == 0) {
#pragma unroll
        for (int c = 0; c < NUM_CLASSES; ++c) shw[wave][c] = pw[c];
    }
    __syncthreads();
    if (threadIdx.x < NUM_CLASSES) {
        const int c = threadIdx.x;
        fw[c] = (float)(shw[0][c] + shw[1][c] + shw[2][c] + shw[3][c]);
    }
    __syncthreads();
    float w[NUM_CLASSES];
#pragma unroll
    for (int c = 0; c < NUM_CLASSES; ++c) w[c] = fw[c];

    // ---- phase 2: stream outputs; async global->LDS staging (wave-private) ----
    // wave chunk = 64 row-pairs = 320 float4 = 5120 B; LDS dst = uniform base + lane*16 (m97 form)
    __shared__ float4 stage4[4][320];  // 20 KiB
    const float4* __restrict__ o4 = (const float4*)outputs;
    const int nchunks = n >> 7;                        // n/128 = 32768
    const int nwaves = gridDim.x * 4;                  // 7168
    const int gwave = blockIdx.x * 4 + wave;
    const int iters = (nchunks + nwaves - 1) / nwaves; // 5, block-uniform

    float sum_log = 0.f, sumsq = 0.f;
    for (int it = 0; it < iters; ++it) {
        const int ch = gwave + it * nwaves;
        const bool valid = ch < nchunks;               // wave-uniform
        __syncthreads();  // prior iteration's LDS reads complete before overwrite
        if (valid) {
            const size_t b4 = (size_t)ch * 320;
#pragma unroll
            for (int k = 0; k < 5; ++k) {
                __builtin_amdgcn_global_load_lds(
                    (const __attribute__((address_space(1))) unsigned int*)(o4 + b4 + k * 64 + lane),
                    (__attribute__((address_space(3))) unsigned int*)(unsigned long)(unsigned long long)
                        (unsigned long long)(uintptr_t)&stage4[wave][k * 64],
                    16, 0, 0);
            }
        }
        __syncthreads();  // drains vmcnt: staged data visible before cross-lane readback
        if (valid) {
            // lane's row-pair: 20 floats at byte offset lane*80 (16B aligned -> 5x ds_read_b128)
            const float4* sp = (const float4*)((const float*)&stage4[wave][0] + lane * 20);
            float4 a = sp[0], b = sp[1], c4 = sp[2], d = sp[3], e = sp[4];
            float r0[NUM_CLASSES] = {a.x, a.y, a.z, a.w, b.x, b.y, b.z, b.w, c4.x, c4.y};
            float r1[NUM_CLASSES] = {c4.z, c4.w, d.x, d.y, d.z, d.w, e.x, e.y, e.z, e.w};
            float nom0 = 0.f, nom1 = 0.f;
#pragma unroll
            for (int c = 0; c < NUM_CLASSES; ++c) {
                nom0 += r0[c] * w[c];
                nom1 += r1[c] * w[c];
                sumsq += r0[c] * r0[c] + r1[c] * r1[c];
            }
            sum_log += __logf(nom0) + __logf(nom1);
        }
    }

    // ---- phase 3: block reduce, publish partial ----
    for (int off = 32; off > 0; off >>= 1) {
        sum_log += __shfl_down(sum_log, off, 64);
        sumsq += __shfl_down(sumsq, off, 64);
    }
    __shared__ float s1[4], s2[4];
    if (lane == 0) { s1[wave] = sum_log; s2[wave] = sumsq; }
    __syncthreads();
    __shared__ bool amLast;
    if (threadIdx.x == 0) {
        pacc[blockIdx.x] = make_float2(s1[0] + s1[1] + s1[2] + s1[3],
                                       s2[0] + s2[1] + s2[2] + s2[3]);
        __threadfence();                               // release partial
        unsigned int t = atomicAdd(done, 1u);          // device-scope
        amLast = (t == gridDim.x - 1);
    }
    __syncthreads();

    // ---- phase 4 (last block only): final reduce + closed-form loss ----
    if (amLast) {
        __threadfence();  // acquire all partials
        float t1 = 0.f, t2 = 0.f;
        for (int i = threadIdx.x; i < B_BLOCKS; i += 256) {
            float2 v = pacc[i];
            t1 += v.x;
            t2 += v.y;
        }
        for (int off = 32; off > 0; off >>= 1) {
            t1 += __shfl_down(t1, off, 64);
            t2 += __shfl_down(t2, off, 64);
        }
        __syncthreads();  // s1/s2 reuse safe
        if (lane == 0) { s1[wave] = t1; s2[wave] = t2; }
        __syncthreads();
        if (threadIdx.x == 0) {
            float a1 = s1[0] + s1[1] + s1[2] + s1[3];
            float a2 = s2[0] + s2[1] + s2[2] + s2[3];
            // mean(-log(nom/denom)) = 0.5*log(sumsq) + 0.5*log(N) - sum_log/N
            out[0] = 0.5f * logf(a2) + 0.5f * logf(fn) - a1 / fn;
        }
    }
}

extern "C" void kernel_launch(void* const* d_in, const int* in_sizes, int n_in,
                              void* d_out, int out_size, void* d_ws, size_t ws_size,
                              hipStream_t stream) {
    const float* outputs = (const float*)d_in[0];
    const int* target = (const int*)d_in[1];
    const int n = in_sizes[1];

    unsigned int* pc = (unsigned int*)d_ws;
    float2* pacc = (float2*)((char*)d_ws + 20480);
    unsigned int* done = (unsigned int*)((char*)d_ws + 34816);

    hist_kernel<<<A_BLOCKS, 256, 0, stream>>>(target, pc, done, n);
    main_kernel<<<B_BLOCKS, 256, 0, stream>>>(outputs, pc, pacc, done, (float*)d_out, n, (float)n);
}

// Round 6
// 247.473 us; speedup vs baseline: 1.3288x; 1.3288x over previous
//
#include <hip/hip_runtime.h>
#include <math.h>

#define NUM_CLASSES 10
#define A_BLOCKS 512
#define B_BLOCKS 2048

// ws layout (every used word overwritten each call; no memset, no atomics):
//   [0)     unsigned pc[A_BLOCKS][NUM_CLASSES]  per-block histograms (20480 B)
//   [20480) float2   pacc[B_BLOCKS]             per-block partials   (16384 B)
//
// R5 post-mortem: global_load_lds staging + barrier-coupled phases ran at
// ~1.7 B/cy/CU (155 us even with L3-resident data). Stream loop must be
// direct loads, barrier-free.

__global__ void __launch_bounds__(256) hist_kernel(const int* __restrict__ target,
                                                   unsigned int* __restrict__ pc, int n) {
    unsigned int cnt[NUM_CLASSES];
#pragma unroll
    for (int c = 0; c < NUM_CLASSES; ++c) cnt[c] = 0u;

    const int tid = blockIdx.x * blockDim.x + threadIdx.x;
    const int stride = gridDim.x * blockDim.x;
    const int4* __restrict__ t4 = (const int4*)target;  // harness passes int32 targets
    const int n4 = n >> 2;

    for (int i = tid; i < n4; i += stride) {
        int4 v = t4[i];
#pragma unroll
        for (int c = 0; c < NUM_CLASSES; ++c) {
            cnt[c] += (unsigned int)(v.x == c) + (unsigned int)(v.y == c) +
                      (unsigned int)(v.z == c) + (unsigned int)(v.w == c);
        }
    }

#pragma unroll
    for (int c = 0; c < NUM_CLASSES; ++c) {
        unsigned int v = cnt[c];
        for (int off = 32; off > 0; off >>= 1)
            v += (unsigned int)__shfl_down((int)v, off, 64);
        cnt[c] = v;
    }

    __shared__ unsigned int sh[4][NUM_CLASSES];
    const int wave = threadIdx.x >> 6;
    if ((threadIdx.x & 63) == 0) {
#pragma unroll
        for (int c = 0; c < NUM_CLASSES; ++c) sh[wave][c] = cnt[c];
    }
    __syncthreads();
    if (threadIdx.x < NUM_CLASSES) {
        const int c = threadIdx.x;
        pc[blockIdx.x * NUM_CLASSES + c] = sh[0][c] + sh[1][c] + sh[2][c] + sh[3][c];
    }
}

__device__ __forceinline__ void process_pair(const float4* __restrict__ o4, size_t p,
                                             const float w[NUM_CLASSES],
                                             float& sum_log, float& sumsq) {
    const float4* base = o4 + p * 5;  // 2 rows = 20 floats = 5 aligned float4
    float4 a = base[0];
    float4 b = base[1];
    float4 c4 = base[2];
    float4 d = base[3];
    float4 e = base[4];
    float r0[NUM_CLASSES] = {a.x, a.y, a.z, a.w, b.x, b.y, b.z, b.w, c4.x, c4.y};
    float r1[NUM_CLASSES] = {c4.z, c4.w, d.x, d.y, d.z, d.w, e.x, e.y, e.z, e.w};
    float nom0 = 0.f, nom1 = 0.f;
#pragma unroll
    for (int c = 0; c < NUM_CLASSES; ++c) {
        nom0 += r0[c] * w[c];
        nom1 += r1[c] * w[c];
        sumsq += r0[c] * r0[c] + r1[c] * r1[c];
    }
    sum_log += __logf(nom0) + __logf(nom1);
}

__global__ void __launch_bounds__(256) main_kernel(const float* __restrict__ outputs,
                                                   const unsigned int* __restrict__ pc,
                                                   float2* __restrict__ pacc, int n) {
    const int wave = threadIdx.x >> 6;
    const int lane = threadIdx.x & 63;

    // ---- phase 1: reduce per-block histograms -> w[10] (block-local) ----
    unsigned int pw[NUM_CLASSES];
#pragma unroll
    for (int c = 0; c < NUM_CLASSES; ++c) pw[c] = 0u;
#pragma unroll
    for (int r = 0; r < A_BLOCKS / 256; ++r) {
        const unsigned int* row = pc + (threadIdx.x + r * 256) * NUM_CLASSES;
#pragma unroll
        for (int c = 0; c < NUM_CLASSES; ++c) pw[c] += row[c];
    }
#pragma unroll
    for (int c = 0; c < NUM_CLASSES; ++c) {
        unsigned int v = pw[c];
        for (int off = 32; off > 0; off >>= 1)
            v += (unsigned int)__shfl_down((int)v, off, 64);
        pw[c] = v;
    }
    __shared__ unsigned int shw[4][NUM_CLASSES];
    __shared__ float fw[NUM_CLASSES];
    if (lane == 0) {
#pragma unroll
        for (int c = 0; c < NUM_CLASSES; ++c) shw[wave][c] = pw[c];
    }
    __syncthreads();
    if (threadIdx.x < NUM_CLASSES) {
        const int c = threadIdx.x;
        fw[c] = (float)(shw[0][c] + shw[1][c] + shw[2][c] + shw[3][c]);
    }
    __syncthreads();
    float w[NUM_CLASSES];
#pragma unroll
    for (int c = 0; c < NUM_CLASSES; ++c) w[c] = fw[c];

    // ---- phase 2: direct-load stream, barrier-free, 2x unrolled for ILP ----
    const float4* __restrict__ o4 = (const float4*)outputs;
    const int npairs = n >> 1;                    // 2^21
    const int stride = gridDim.x * blockDim.x;    // 524288 -> exactly 4 pairs/thread
    const int tid = blockIdx.x * blockDim.x + threadIdx.x;

    float sum_log = 0.f, sumsq = 0.f;
    for (int p = tid; p < npairs; p += 2 * stride) {
        process_pair(o4, (size_t)p, w, sum_log, sumsq);
        const int p2 = p + stride;
        if (p2 < npairs) process_pair(o4, (size_t)p2, w, sum_log, sumsq);
    }

    // ---- phase 3: block reduce, plain store of per-block partial ----
    for (int off = 32; off > 0; off >>= 1) {
        sum_log += __shfl_down(sum_log, off, 64);
        sumsq += __shfl_down(sumsq, off, 64);
    }
    __shared__ float s1[4], s2[4];
    if (lane == 0) { s1[wave] = sum_log; s2[wave] = sumsq; }
    __syncthreads();
    if (threadIdx.x == 0) {
        pacc[blockIdx.x] = make_float2(s1[0] + s1[1] + s1[2] + s1[3],
                                       s2[0] + s2[1] + s2[2] + s2[3]);
    }
}

__global__ void __launch_bounds__(256) finalize_kernel(const float2* __restrict__ pacc,
                                                       float* __restrict__ out, float fn) {
    float sum_log = 0.f, sumsq = 0.f;
    for (int i = threadIdx.x; i < B_BLOCKS; i += 256) {
        float2 v = pacc[i];
        sum_log += v.x;
        sumsq += v.y;
    }
    for (int off = 32; off > 0; off >>= 1) {
        sum_log += __shfl_down(sum_log, off, 64);
        sumsq += __shfl_down(sumsq, off, 64);
    }
    __shared__ float s1[4], s2[4];
    const int wave = threadIdx.x >> 6;
    if ((threadIdx.x & 63) == 0) { s1[wave] = sum_log; s2[wave] = sumsq; }
    __syncthreads();
    if (threadIdx.x == 0) {
        float t1 = s1[0] + s1[1] + s1[2] + s1[3];
        float t2 = s2[0] + s2[1] + s2[2] + s2[3];
        // mean(-log(nom/denom)) = 0.5*log(sumsq) + 0.5*log(N) - sum_log/N
        out[0] = 0.5f * logf(t2) + 0.5f * logf(fn) - t1 / fn;
    }
}

extern "C" void kernel_launch(void* const* d_in, const int* in_sizes, int n_in,
                              void* d_out, int out_size, void* d_ws, size_t ws_size,
                              hipStream_t stream) {
    const float* outputs = (const float*)d_in[0];
    const int* target = (const int*)d_in[1];
    const int n = in_sizes[1];

    unsigned int* pc = (unsigned int*)d_ws;
    float2* pacc = (float2*)((char*)d_ws + 20480);

    hist_kernel<<<A_BLOCKS, 256, 0, stream>>>(target, pc, n);
    main_kernel<<<B_BLOCKS, 256, 0, stream>>>(outputs, pc, pacc, n);
    finalize_kernel<<<1, 256, 0, stream>>>(pacc, (float*)d_out, (float)n);
}